// Round 1
// baseline (250.636 us; speedup 1.0000x reference)
//
#include <hip/hip_runtime.h>
#include <hip/hip_bf16.h>

// Problem constants (reference: B,S,D,K = 4, 8192, 512, 20)
#define BB 4
#define SS 8192
#define DD 512
#define KK 20
#define CHUNKS 64           // k2 chunks per batch (S/128 tokens each)

// ---------------------------------------------------------------------------
// K0: per-splat params: params[k]=||c_k||^2, params[K+k]=0.5/sigma^2, params[2K+k]=amp
// ---------------------------------------------------------------------------
__global__ void k0_params(const float* __restrict__ pos,
                          const float* __restrict__ log_scales,
                          const float* __restrict__ amps,
                          float* __restrict__ params) {
  int k = blockIdx.x;
  int lane = threadIdx.x;
  float acc = 0.f;
  for (int d = lane; d < DD; d += 64) { float p = pos[k * DD + d]; acc += p * p; }
#pragma unroll
  for (int off = 32; off > 0; off >>= 1) acc += __shfl_xor(acc, off);
  if (lane == 0) {
    params[k] = acc;                       // c2
    float s = __expf(log_scales[k]);
    params[KK + k] = 0.5f / (s * s);       // alpha
    params[2 * KK + k] = amps[k];          // amplitude
  }
}

// ---------------------------------------------------------------------------
// K1: attn[b,s,k] = amp_k*exp(-alpha_k*max(x2-2xc+c2,0)) / (sum_k + 1e-8)
// 256 thr = 64 tokens x 4 d-sublanes. Each 4-lane group covers one token's
// 512 dims (stride-16 float4), so each wave global-load instr consumes 16
// full 64B lines. Positions broadcast from LDS. Reduce via shfl_xor(1|2).
// ---------------------------------------------------------------------------
__global__ __launch_bounds__(256) void k1_attn(
    const float* __restrict__ x, const float* __restrict__ pos,
    const float* __restrict__ params, float* __restrict__ attn) {
  __shared__ float pos_s[KK * DD];  // 40 KB
  int tid = threadIdx.x;
  for (int i = tid; i < KK * DD / 4; i += 256)
    ((float4*)pos_s)[i] = ((const float4*)pos)[i];
  __syncthreads();

  int tl = tid >> 2;      // local token 0..63
  int dsub = tid & 3;     // d-sublane 0..3
  size_t tok = (size_t)blockIdx.x * 64 + tl;
  const float* xrow = x + tok * DD;

  float acc[KK];
#pragma unroll
  for (int k = 0; k < KK; ++k) acc[k] = 0.f;
  float x2 = 0.f;

#pragma unroll 4
  for (int j = 0; j < 32; ++j) {
    int d0 = j * 16 + dsub * 4;
    float4 xv = *(const float4*)(xrow + d0);
    x2 += xv.x * xv.x + xv.y * xv.y + xv.z * xv.z + xv.w * xv.w;
#pragma unroll
    for (int k = 0; k < KK; ++k) {
      float4 p = *(const float4*)(pos_s + k * DD + d0);
      acc[k] += xv.x * p.x + xv.y * p.y + xv.z * p.z + xv.w * p.w;
    }
  }
  // combine the 4 d-sublanes of each token
#pragma unroll
  for (int k = 0; k < KK; ++k) {
    acc[k] += __shfl_xor(acc[k], 1);
    acc[k] += __shfl_xor(acc[k], 2);
  }
  x2 += __shfl_xor(x2, 1);
  x2 += __shfl_xor(x2, 2);

  if (dsub == 0) {
    float g[KK];
    float sum = 0.f;
#pragma unroll
    for (int k = 0; k < KK; ++k) {
      float d2 = fmaxf(x2 - 2.f * acc[k] + params[k], 0.f);
      float gk = params[2 * KK + k] * __expf(-params[KK + k] * d2);
      g[k] = gk;
      sum += gk;
    }
    float inv = 1.f / (sum + 1e-8f);
    float* arow = attn + tok * KK;
#pragma unroll
    for (int k = 0; k < KK; ++k) arow[k] = g[k] * inv;
  }
}

// ---------------------------------------------------------------------------
// K2: per-(batch,chunk) partial of M[b,k,d] = sum_s attn[b,s,k]*x[b,s,d].
// Thread owns a float2 d-slot, accumulates all 20 k's in registers (40 VGPR),
// writes its partial slab. Deterministic (no atomics).
// ---------------------------------------------------------------------------
__global__ __launch_bounds__(256) void k2_scatter(
    const float* __restrict__ x, const float* __restrict__ attn,
    float* __restrict__ Mpart) {
  int t = threadIdx.x;
  int c = blockIdx.x;       // chunk 0..63
  int b = blockIdx.y;
  int s0 = c * (SS / CHUNKS);

  float2 Ml[KK];
#pragma unroll
  for (int k = 0; k < KK; ++k) Ml[k] = make_float2(0.f, 0.f);

  for (int s = s0; s < s0 + SS / CHUNKS; ++s) {
    size_t tokb = (size_t)b * SS + s;
    float2 xv = *(const float2*)(x + tokb * DD + 2 * t);
    const float* arow = attn + tokb * KK;  // lane-uniform -> scalar loads
#pragma unroll
    for (int k = 0; k < KK; ++k) {
      float a = arow[k];
      Ml[k].x += a * xv.x;
      Ml[k].y += a * xv.y;
    }
  }
  float* base = Mpart + (((size_t)b * CHUNKS + c) * KK) * DD + 2 * t;
#pragma unroll
  for (int k = 0; k < KK; ++k)
    *(float2*)(base + (size_t)k * DD) = Ml[k];
}

// K2b: M[b,k,d] = sum_c Mpart[b,c,k,d]  (deterministic order)
__global__ __launch_bounds__(256) void k2b_reduce(
    const float* __restrict__ Mpart, float* __restrict__ Mg) {
  int idx = blockIdx.x * 256 + threadIdx.x;  // 0 .. B*K*D-1 (=40960)
  int b = idx / (KK * DD);
  int kd = idx - b * (KK * DD);
  const float* p = Mpart + (size_t)b * CHUNKS * KK * DD + kd;
  float acc = 0.f;
#pragma unroll 8
  for (int c = 0; c < CHUNKS; ++c) acc += p[(size_t)c * KK * DD];
  Mg[idx] = acc;
}

// ---------------------------------------------------------------------------
// K3: out[r,e] = sum_d in[r,d] * W[e,d]   for 80 rows (r = b*K+k).
// grid (80, 2); block computes 256 e's; input row staged in LDS (broadcast).
// ---------------------------------------------------------------------------
__global__ __launch_bounds__(256) void k3_proj(
    const float* __restrict__ in, const float* __restrict__ W,
    float* __restrict__ out) {
  __shared__ float row_s[DD];
  int bk = blockIdx.x;
  int t = threadIdx.x;
  for (int i = t; i < DD / 4; i += 256)
    ((float4*)row_s)[i] = ((const float4*)(in + (size_t)bk * DD))[i];
  __syncthreads();
  int e = blockIdx.y * 256 + t;
  const float* wrow = W + (size_t)e * DD;
  float acc = 0.f;
#pragma unroll 4
  for (int j = 0; j < DD / 4; ++j) {
    float4 w4 = *(const float4*)(wrow + 4 * j);
    float4 m4 = ((const float4*)row_s)[j];
    acc += m4.x * w4.x + m4.y * w4.y + m4.z * w4.z + m4.w * w4.w;
  }
  out[(size_t)bk * DD + e] = acc;
}

// ---------------------------------------------------------------------------
// K5: out[b,s,e] = sum_k attn[b,s,k] * ws2[b,k,e].
// Thread owns a float2 e-slot; ws2 slice (20 float2) held in registers.
// ---------------------------------------------------------------------------
__global__ __launch_bounds__(256) void k5_gather(
    const float* __restrict__ attn, const float* __restrict__ ws2,
    float* __restrict__ out) {
  int t = threadIdx.x;
  int b = blockIdx.y;
  int s0 = blockIdx.x * (SS / CHUNKS);

  float2 w[KK];
#pragma unroll
  for (int k = 0; k < KK; ++k)
    w[k] = *(const float2*)(ws2 + ((size_t)b * KK + k) * DD + 2 * t);

  for (int s = s0; s < s0 + SS / CHUNKS; ++s) {
    size_t tokb = (size_t)b * SS + s;
    const float* arow = attn + tokb * KK;  // lane-uniform -> scalar loads
    float2 o = make_float2(0.f, 0.f);
#pragma unroll
    for (int k = 0; k < KK; ++k) {
      float a = arow[k];
      o.x += a * w[k].x;
      o.y += a * w[k].y;
    }
    *(float2*)(out + tokb * DD + 2 * t) = o;
  }
}

// ---------------------------------------------------------------------------
extern "C" void kernel_launch(void* const* d_in, const int* in_sizes, int n_in,
                              void* d_out, int out_size, void* d_ws, size_t ws_size,
                              hipStream_t stream) {
  const float* x   = (const float*)d_in[0];
  const float* pos = (const float*)d_in[1];
  const float* ls  = (const float*)d_in[2];
  const float* am  = (const float*)d_in[3];
  const float* w_v = (const float*)d_in[4];
  const float* w_o = (const float*)d_in[5];
  float* out = (float*)d_out;

  float* ws     = (float*)d_ws;
  float* params = ws;                                   // 64 floats
  float* attn   = ws + 64;                              // B*S*K = 655360
  float* Mg     = attn + (size_t)BB * SS * KK;          // B*K*D = 40960
  float* ssb    = Mg + (size_t)BB * KK * DD;            // 40960
  float* ws2    = ssb + (size_t)BB * KK * DD;           // 40960
  float* Mpart  = ws2 + (size_t)BB * KK * DD;           // B*CHUNKS*K*D = 2621440
  // total ~3.4 M floats ~ 13.4 MB of workspace

  k0_params<<<KK, 64, 0, stream>>>(pos, ls, am, params);
  k1_attn<<<(BB * SS) / 64, 256, 0, stream>>>(x, pos, params, attn);
  k2_scatter<<<dim3(CHUNKS, BB), 256, 0, stream>>>(x, attn, Mpart);
  k2b_reduce<<<(BB * KK * DD) / 256, 256, 0, stream>>>(Mpart, Mg);
  k3_proj<<<dim3(BB * KK, 2), 256, 0, stream>>>(Mg, w_v, ssb);   // splat_states
  k3_proj<<<dim3(BB * KK, 2), 256, 0, stream>>>(ssb, w_o, ws2);  // splat_states @ w_o^T
  k5_gather<<<dim3(CHUNKS, BB), 256, 0, stream>>>(attn, ws2, out);
}